// Round 6
// baseline (3041.538 us; speedup 1.0000x reference)
//
#include <hip/hip_runtime.h>
#include <hip/hip_bf16.h>

#define HF 64
#define BINSZ 256          // dst rows per coarse bin
#define PCHUNK 4096        // edges per partition chunk

// ---------------- proj news: relu([M,385] @ [385,64] + b) ----------------
__global__ __launch_bounds__(256) void k_proj_news(
    const float* __restrict__ A, const float* __restrict__ W,
    const float* __restrict__ b, float* __restrict__ out, int M)
{
    __shared__ float As[16][68];
    __shared__ float Ws[16][64];
    const int t = threadIdx.x;
    const int r0 = blockIdx.x * 64;
    const int rt = t >> 4, ct = t & 15;
    float acc[4][4] = {};

    for (int c0 = 0; c0 < 385; c0 += 16) {
        int lr = t >> 2, lk0 = (t & 3) * 4;
        #pragma unroll
        for (int j = 0; j < 4; ++j) {
            int k = c0 + lk0 + j;
            float v = 0.f;
            if ((r0 + lr) < M && k < 385) v = A[(size_t)(r0 + lr) * 385 + k];
            As[lk0 + j][lr] = v;
        }
        #pragma unroll
        for (int j = 0; j < 4; ++j) {
            int idx = j * 256 + t;
            int k = idx >> 6, col = idx & 63;
            float v = 0.f;
            if (c0 + k < 385) v = W[(size_t)(c0 + k) * 64 + col];
            Ws[k][col] = v;
        }
        __syncthreads();
        #pragma unroll
        for (int kk = 0; kk < 16; ++kk) {
            float4 a = *(const float4*)&As[kk][rt * 4];
            float4 w = *(const float4*)&Ws[kk][ct * 4];
            float av[4] = {a.x, a.y, a.z, a.w};
            float wv[4] = {w.x, w.y, w.z, w.w};
            #pragma unroll
            for (int i = 0; i < 4; ++i)
                #pragma unroll
                for (int j = 0; j < 4; ++j)
                    acc[i][j] += av[i] * wv[j];
        }
        __syncthreads();
    }
    float4 bv = *(const float4*)&b[ct * 4];
    float bb[4] = {bv.x, bv.y, bv.z, bv.w};
    #pragma unroll
    for (int i = 0; i < 4; ++i) {
        int row = r0 + rt * 4 + i;
        if (row < M) {
            float4 o;
            o.x = fmaxf(acc[i][0] + bb[0], 0.f);
            o.y = fmaxf(acc[i][1] + bb[1], 0.f);
            o.z = fmaxf(acc[i][2] + bb[2], 0.f);
            o.w = fmaxf(acc[i][3] + bb[3], 0.f);
            *(float4*)&out[(size_t)row * HF + ct * 4] = o;
        }
    }
}

// ---------------- proj company ----------------
__global__ __launch_bounds__(256) void k_proj_comp(
    const float* __restrict__ A, const float* __restrict__ W,
    const float* __restrict__ b, float* __restrict__ out, int M)
{
    int idx = blockIdx.x * blockDim.x + threadIdx.x;
    if (idx >= M * HF) return;
    int row = idx >> 6, col = idx & 63;
    float acc = b[col];
    #pragma unroll
    for (int k = 0; k < 24; ++k)
        acc += A[(size_t)row * 24 + k] * W[k * HF + col];
    out[idx] = fmaxf(acc, 0.f);
}

// ---------------- per-dst edge count ----------------
__global__ void k_count(const int* __restrict__ dst, int n, int base,
                        unsigned* __restrict__ cnt)
{
    for (int i = blockIdx.x * blockDim.x + threadIdx.x; i < n;
         i += gridDim.x * blockDim.x)
        atomicAdd(&cnt[base + dst[i]], 1u);
}

// ---------------- inv = 1/max(cnt,1) ----------------
__global__ void k_inv(const unsigned* __restrict__ cnt, float* __restrict__ inv, int n)
{
    int i = blockIdx.x * blockDim.x + threadIdx.x;
    if (i < n) inv[i] = 1.0f / fmaxf((float)cnt[i], 1.0f);
}

// ---------------- bin histogram: bin = dst >> 8 ----------------
template<int NB>
__global__ __launch_bounds__(256) void k_binhist(
    const int* __restrict__ dst, int n, unsigned* __restrict__ bins)
{
    __shared__ unsigned h[NB];
    for (int i = threadIdx.x; i < NB; i += 256) h[i] = 0;
    __syncthreads();
    for (int i = blockIdx.x * blockDim.x + threadIdx.x; i < n;
         i += gridDim.x * blockDim.x)
        atomicAdd(&h[dst[i] >> 8], 1u);
    __syncthreads();
    for (int i = threadIdx.x; i < NB; i += 256)
        if (h[i]) atomicAdd(&bins[i], h[i]);
}

// ---------------- single-block exclusive scan ----------------
__global__ __launch_bounds__(1024) void k_scan(
    const unsigned* __restrict__ cnt, int n,
    int* __restrict__ off, int* __restrict__ cursor)
{
    __shared__ int wsum[17];
    __shared__ int carry_s;
    if (threadIdx.x == 0) carry_s = 0;
    __syncthreads();
    const int lane = threadIdx.x & 63, wid = threadIdx.x >> 6;
    for (int base = 0; base < n; base += 1024) {
        int i = base + (int)threadIdx.x;
        int v = (i < n) ? (int)cnt[i] : 0;
        int x = v;
        #pragma unroll
        for (int s = 1; s < 64; s <<= 1) {
            int t = __shfl_up(x, s, 64);
            if (lane >= s) x += t;
        }
        if (lane == 63) wsum[wid] = x;
        __syncthreads();
        if (threadIdx.x == 0) {
            int run = 0;
            #pragma unroll
            for (int w = 0; w < 16; ++w) { int t = wsum[w]; wsum[w] = run; run += t; }
            wsum[16] = run;
        }
        __syncthreads();
        int excl = x - v + wsum[wid] + carry_s;
        if (i < n) { off[i] = excl; cursor[i] = excl; }
        __syncthreads();
        if (threadIdx.x == 0) carry_s += wsum[16];
        __syncthreads();
    }
    if (threadIdx.x == 0) off[n] = carry_s;
}

// ---------------- partition edges into coarse bins (block counting sort) ----------------
template<int NB>
__global__ __launch_bounds__(256) void k_partition(
    const int* __restrict__ src, const int* __restrict__ dst, int n,
    int* __restrict__ cursor, unsigned* __restrict__ binned)
{
    __shared__ unsigned stage[PCHUNK];   // packed src | dl<<17 (dl 8 bits)
    __shared__ int hist[NB];
    __shared__ int rank[NB];
    __shared__ int base[NB];
    for (long long c0 = (long long)blockIdx.x * PCHUNK; c0 < n;
         c0 += (long long)gridDim.x * PCHUNK) {
        int nc = min((long long)PCHUNK, (long long)n - c0);
        for (int i = threadIdx.x; i < NB; i += 256) { hist[i] = 0; rank[i] = 0; }
        __syncthreads();
        for (int i = threadIdx.x; i < nc; i += 256) {
            int d = dst[c0 + i];
            stage[i] = (unsigned)src[c0 + i] | ((unsigned)(d & 255) << 17);
            atomicAdd(&hist[d >> 8], 1);
        }
        __syncthreads();
        for (int i = threadIdx.x; i < NB; i += 256)
            if (hist[i]) base[i] = atomicAdd(&cursor[i], hist[i]);
        __syncthreads();
        for (int i = threadIdx.x; i < nc; i += 256) {
            int b = dst[c0 + i] >> 8;
            int r = atomicAdd(&rank[b], 1);
            binned[base[b] + r] = stage[i];
        }
        __syncthreads();
    }
}

// ---------------- binned LDS aggregation, (bin, quarter, sub) per block ----------------
// Block owns 64 dst rows = quarter q of coarse bin; scans 1/S of the bin's edges.
template<int S>
__global__ __launch_bounds__(256) void k_binagg(
    const unsigned* __restrict__ binned, const int* __restrict__ bin_off,
    const float* __restrict__ feat, float* __restrict__ sum, int M)
{
    __shared__ float acc[64 * HF];    // 16 KiB
    const int tid = threadIdx.x, lane = tid & 63, wv = tid >> 6;  // 4 waves
    #pragma unroll
    for (int i = 0; i < 4; ++i)
        ((float4*)acc)[tid + i * 256] = make_float4(0.f, 0.f, 0.f, 0.f);
    __syncthreads();
    const int bx = blockIdx.x;
    const int bin = bx / (4 * S);
    const int rem = bx % (4 * S);
    const unsigned q = (unsigned)(rem / S);
    const int sub = rem % S;
    const int e0 = bin_off[bin], e1 = bin_off[bin + 1];
    const int len = (e1 - e0 + S - 1) / S;
    const int s0 = e0 + sub * len;
    const int s1 = min(s0 + len, e1);
    for (int eb = s0 + wv * 4; eb < s1; eb += 16) {
        int m = s1 - eb;
        unsigned p0 = binned[eb];
        unsigned p1 = (m > 1) ? binned[eb + 1] : 0u;
        unsigned p2 = (m > 2) ? binned[eb + 2] : 0u;
        unsigned p3 = (m > 3) ? binned[eb + 3] : 0u;
        bool u0 = (p0 >> 23) == q;
        bool u1 = (m > 1) && ((p1 >> 23) == q);
        bool u2 = (m > 2) && ((p2 >> 23) == q);
        bool u3 = (m > 3) && ((p3 >> 23) == q);
        float v0 = u0 ? feat[(size_t)(p0 & 0x1FFFF) * HF + lane] : 0.f;
        float v1 = u1 ? feat[(size_t)(p1 & 0x1FFFF) * HF + lane] : 0.f;
        float v2 = u2 ? feat[(size_t)(p2 & 0x1FFFF) * HF + lane] : 0.f;
        float v3 = u3 ? feat[(size_t)(p3 & 0x1FFFF) * HF + lane] : 0.f;
        if (u0) atomicAdd(&acc[((p0 >> 17) & 63) * HF + lane], v0);
        if (u1) atomicAdd(&acc[((p1 >> 17) & 63) * HF + lane], v1);
        if (u2) atomicAdd(&acc[((p2 >> 17) & 63) * HF + lane], v2);
        if (u3) atomicAdd(&acc[((p3 >> 17) & 63) * HF + lane], v3);
    }
    __syncthreads();
    const int d0 = bin * BINSZ + (int)q * 64;
    #pragma unroll
    for (int r = wv; r < 64; r += 4) {
        int row = d0 + r;
        if (row < M)
            atomicAdd(&sum[(size_t)row * HF + lane], acc[r * HF + lane]);
    }
}

// ---------------- atomic scatter (tiny relations) ----------------
__global__ __launch_bounds__(256) void k_agg(
    const int* __restrict__ src, const int* __restrict__ dst,
    const float* __restrict__ x, float* __restrict__ sum, int n)
{
    const int lane = threadIdx.x & 63;
    int w = (blockIdx.x * blockDim.x + threadIdx.x) >> 6;
    const int nw = (gridDim.x * blockDim.x) >> 6;
    for (int e = w; e < n; e += nw) {
        int s = src[e], d = dst[e];
        float v = x[(size_t)s * HF + lane];
        atomicAdd(&sum[(size_t)d * HF + lane], v);
    }
}

// ---------------- news layer-1: xn = LN(relu(sum*inv @ Wl + bl + xn0 @ Wr)) ----------------
__global__ __launch_bounds__(256) void k_news_l1(
    const float* __restrict__ sum_sim, const float* __restrict__ invc,
    const float* __restrict__ xn0,
    const float* __restrict__ Wl, const float* __restrict__ bl,
    const float* __restrict__ Wr,
    const float* __restrict__ g, const float* __restrict__ be,
    float* __restrict__ xn, int M)
{
    __shared__ float A1[64][68];
    __shared__ float A2[64][68];
    const int t = threadIdx.x;
    const int r0 = blockIdx.x * 64;
    const int lrow = t & 63;
    const int wq = t >> 6;

    bool rok = (r0 + lrow) < M;
    float invr = rok ? invc[r0 + lrow] : 0.f;
    #pragma unroll
    for (int j4 = 0; j4 < 4; ++j4) {
        int k0 = wq * 16 + j4 * 4;
        float4 v1 = make_float4(0.f, 0.f, 0.f, 0.f), v2 = v1;
        if (rok) {
            v1 = *(const float4*)&sum_sim[(size_t)(r0 + lrow) * HF + k0];
            v2 = *(const float4*)&xn0[(size_t)(r0 + lrow) * HF + k0];
        }
        A1[k0 + 0][lrow] = v1.x * invr; A1[k0 + 1][lrow] = v1.y * invr;
        A1[k0 + 2][lrow] = v1.z * invr; A1[k0 + 3][lrow] = v1.w * invr;
        A2[k0 + 0][lrow] = v2.x; A2[k0 + 1][lrow] = v2.y;
        A2[k0 + 2][lrow] = v2.z; A2[k0 + 3][lrow] = v2.w;
    }
    __syncthreads();

    const int rt = t >> 4, ct = t & 15;
    float acc[4][4] = {};
    #pragma unroll 16
    for (int kk = 0; kk < 64; ++kk) {
        float4 a1 = *(const float4*)&A1[kk][rt * 4];
        float4 a2 = *(const float4*)&A2[kk][rt * 4];
        float4 wl = *(const float4*)&Wl[(size_t)kk * HF + ct * 4];
        float4 wr = *(const float4*)&Wr[(size_t)kk * HF + ct * 4];
        float a1v[4] = {a1.x, a1.y, a1.z, a1.w};
        float a2v[4] = {a2.x, a2.y, a2.z, a2.w};
        float wlv[4] = {wl.x, wl.y, wl.z, wl.w};
        float wrv[4] = {wr.x, wr.y, wr.z, wr.w};
        #pragma unroll
        for (int i = 0; i < 4; ++i)
            #pragma unroll
            for (int j = 0; j < 4; ++j)
                acc[i][j] += a1v[i] * wlv[j] + a2v[i] * wrv[j];
    }
    __syncthreads();
    float (*C)[68] = A1;
    float4 blv = *(const float4*)&bl[ct * 4];
    float blb[4] = {blv.x, blv.y, blv.z, blv.w};
    #pragma unroll
    for (int i = 0; i < 4; ++i) {
        float4 o;
        o.x = fmaxf(acc[i][0] + blb[0], 0.f);
        o.y = fmaxf(acc[i][1] + blb[1], 0.f);
        o.z = fmaxf(acc[i][2] + blb[2], 0.f);
        o.w = fmaxf(acc[i][3] + blb[3], 0.f);
        *(float4*)&C[rt * 4 + i][ct * 4] = o;
    }
    __syncthreads();

    const int lane = t & 63, wid = t >> 6;
    float gl = g[lane], bel = be[lane];
    for (int rr = 0; rr < 16; ++rr) {
        int row = wid * 16 + rr;
        float v = C[row][lane];
        float s = v, q = v * v;
        #pragma unroll
        for (int m = 1; m < 64; m <<= 1) {
            s += __shfl_xor(s, m, 64);
            q += __shfl_xor(q, m, 64);
        }
        float mean = s * (1.f / 64.f);
        float var = q * (1.f / 64.f) - mean * mean;
        float r = rsqrtf(var + 1e-5f);
        int grow = r0 + row;
        if (grow < M) xn[(size_t)grow * HF + lane] = (v - mean) * r * gl + bel;
    }
}

// ---------------- company layer-1 ----------------
__global__ __launch_bounds__(256) void k_comp_l1(
    const float* __restrict__ sum_men, const float* __restrict__ inv_men,
    const float* __restrict__ sum_rel, const float* __restrict__ inv_rel,
    const float* __restrict__ xc0,
    const float* __restrict__ Wl1, const float* __restrict__ bl1,
    const float* __restrict__ Wr1,
    const float* __restrict__ Wl2, const float* __restrict__ bl2,
    const float* __restrict__ Wr2,
    const float* __restrict__ g, const float* __restrict__ be,
    float* __restrict__ xc, int M)
{
    const int lane = threadIdx.x & 63;
    const int node = (int)((blockIdx.x * blockDim.x + threadIdx.x) >> 6);
    if (node >= M) return;
    float mm = sum_men[(size_t)node * HF + lane] * inv_men[node];
    float mr = sum_rel[(size_t)node * HF + lane] * inv_rel[node];
    float xv = xc0[(size_t)node * HF + lane];
    float acc = bl1[lane] + bl2[lane];
    #pragma unroll 8
    for (int k = 0; k < 64; ++k) {
        float amm = __shfl(mm, k, 64);
        float amr = __shfl(mr, k, 64);
        float ax  = __shfl(xv, k, 64);
        acc += amm * Wl1[k * HF + lane] + ax * Wr1[k * HF + lane]
             + amr * Wl2[k * HF + lane] + ax * Wr2[k * HF + lane];
    }
    float pre = fmaxf(acc + xv, 0.f);
    float s = pre, q = pre * pre;
    #pragma unroll
    for (int m = 1; m < 64; m <<= 1) {
        s += __shfl_xor(s, m, 64);
        q += __shfl_xor(q, m, 64);
    }
    float mean = s * (1.f / 64.f);
    float var = q * (1.f / 64.f) - mean * mean;
    float r = rsqrtf(var + 1e-5f);
    xc[(size_t)node * HF + lane] = (pre - mean) * r * g[lane] + be[lane];
}

// ---------------- company layer-2 + classifier ----------------
__global__ __launch_bounds__(256) void k_final(
    const float* __restrict__ sum_men, const float* __restrict__ inv_men,
    const float* __restrict__ sum_rel, const float* __restrict__ inv_rel,
    const float* __restrict__ xc,
    const float* __restrict__ Wl1, const float* __restrict__ bl1,
    const float* __restrict__ Wr1,
    const float* __restrict__ Wl2, const float* __restrict__ bl2,
    const float* __restrict__ Wr2,
    const float* __restrict__ W1, const float* __restrict__ b1,
    const float* __restrict__ W2, const float* __restrict__ b2,
    float* __restrict__ out, int M)
{
    const int lane = threadIdx.x & 63;
    const int node = (int)((blockIdx.x * blockDim.x + threadIdx.x) >> 6);
    if (node >= M) return;
    float mm = sum_men[(size_t)node * HF + lane] * inv_men[node];
    float mr = sum_rel[(size_t)node * HF + lane] * inv_rel[node];
    float xv = xc[(size_t)node * HF + lane];
    float acc = bl1[lane] + bl2[lane];
    #pragma unroll 8
    for (int k = 0; k < 64; ++k) {
        float amm = __shfl(mm, k, 64);
        float amr = __shfl(mr, k, 64);
        float ax  = __shfl(xv, k, 64);
        acc += amm * Wl1[k * HF + lane] + ax * (Wr1[k * HF + lane] + Wr2[k * HF + lane])
             + amr * Wl2[k * HF + lane];
    }
    float comp = fmaxf(acc + xv, 0.f);
    const int l31 = lane & 31;
    float hacc = b1[l31];
    #pragma unroll 8
    for (int j = 0; j < 64; ++j) {
        float cj = __shfl(comp, j, 64);
        hacc += cj * W1[j * 32 + l31];
    }
    float h = fmaxf(hacc, 0.f);
    float p = (lane < 32) ? h * W2[l31] : 0.f;
    #pragma unroll
    for (int m = 16; m >= 1; m >>= 1) p += __shfl_xor(p, m, 64);
    if (lane == 0) out[node] = p + b2[0];
}

extern "C" void kernel_launch(void* const* d_in, const int* in_sizes, int n_in,
                              void* d_out, int out_size, void* d_ws, size_t ws_size,
                              hipStream_t stream)
{
    const float* x_news  = (const float*)d_in[0];
    const float* x_comp  = (const float*)d_in[1];
    const int*   edge_sim = (const int*)d_in[2];
    const int*   men_src  = (const int*)d_in[3];
    const int*   men_dst  = (const int*)d_in[4];
    const int*   edge_rel = (const int*)d_in[5];
    const float* nw_W = (const float*)d_in[6];
    const float* nw_b = (const float*)d_in[7];
    const float* cw_W = (const float*)d_in[8];
    const float* cw_b = (const float*)d_in[9];
    const float* n1n_g = (const float*)d_in[10];
    const float* n1n_b = (const float*)d_in[11];
    const float* n1c_g = (const float*)d_in[12];
    const float* n1c_b = (const float*)d_in[13];
    const float* c1_Wl = (const float*)d_in[14];
    const float* c1_bl = (const float*)d_in[15];
    const float* c1_Wr = (const float*)d_in[16];
    const float* c2_Wl = (const float*)d_in[17];
    const float* c2_bl = (const float*)d_in[18];
    const float* c2_Wr = (const float*)d_in[19];
    const float* cls_W1 = (const float*)d_in[20];
    const float* cls_b1 = (const float*)d_in[21];
    const float* cls_W2 = (const float*)d_in[22];
    const float* cls_b2 = (const float*)d_in[23];

    const int Nn = in_sizes[0] / 385;        // 100000
    const int Nc = in_sizes[1] / 24;         // 5000
    const int Es = in_sizes[2] / 2;
    const int Em = in_sizes[3];
    const int Er = in_sizes[5] / 2;
    const int* sim_src = edge_sim;
    const int* sim_dst = edge_sim + Es;
    const int* rel_src = edge_rel;
    const int* rel_dst = edge_rel + Er;

    const int NBS = (Nn + BINSZ - 1) / BINSZ;   // 392 sim bins
    const int NBM = (Nc + BINSZ - 1) / BINSZ;   // 20 men bins

    float* ws = (float*)d_ws;
    size_t o = 0;
    // ---- zeroed region ----
    unsigned* cnt_all = (unsigned*)(ws + o); o += (size_t)Nn + 2 * Nc;
    unsigned* binh_s  = (unsigned*)(ws + o); o += 400;
    unsigned* binh_m  = (unsigned*)(ws + o); o += 32;
    float* sum_sim  = ws + o; o += (size_t)Nn * HF;
    float* sum_men1 = ws + o; o += (size_t)Nc * HF;
    float* sum_rel1 = ws + o; o += (size_t)Nc * HF;
    float* sum_men2 = ws + o; o += (size_t)Nc * HF;
    float* sum_rel2 = ws + o; o += (size_t)Nc * HF;
    const size_t zero_bytes = o * sizeof(float);
    // ---- rest ----
    float* inv_all = ws + o; o += (size_t)Nn + 2 * Nc;
    int* boff_s = (int*)(ws + o); o += 401;
    int* bcur_s = (int*)(ws + o); o += 400;
    int* boff_m = (int*)(ws + o); o += 33;
    int* bcur_m = (int*)(ws + o); o += 32;
    unsigned* binned_s = (unsigned*)(ws + o); o += Es;
    unsigned* binned_m = (unsigned*)(ws + o); o += Em;
    float* xn0 = ws + o; o += (size_t)Nn * HF;   // layer-1 output written in-place
    float* xc0 = ws + o; o += (size_t)Nc * HF;
    float* xc  = ws + o; o += (size_t)Nc * HF;

    unsigned* cnt_sim = cnt_all;
    float* inv_sim = inv_all;
    float* inv_men = inv_all + Nn;
    float* inv_rel = inv_all + Nn + Nc;

    hipMemsetAsync(ws, 0, zero_bytes, stream);

    // projections
    k_proj_news<<<(Nn + 63) / 64, 256, 0, stream>>>(x_news, nw_W, nw_b, xn0, Nn);
    k_proj_comp<<<(Nc * HF + 255) / 256, 256, 0, stream>>>(x_comp, cw_W, cw_b, xc0, Nc);

    // degree counts + inverses
    k_count<<<1024, 256, 0, stream>>>(sim_dst, Es, 0, cnt_all);
    k_count<<<512, 256, 0, stream>>>(men_dst, Em, Nn, cnt_all);
    k_count<<<256, 256, 0, stream>>>(rel_dst, Er, Nn + Nc, cnt_all);
    k_inv<<<(Nn + 2 * Nc + 255) / 256, 256, 0, stream>>>(cnt_all, inv_all, Nn + 2 * Nc);

    // coarse binning (sim + men)
    k_binhist<400><<<512, 256, 0, stream>>>(sim_dst, Es, binh_s);
    k_binhist<32><<<256, 256, 0, stream>>>(men_dst, Em, binh_m);
    k_scan<<<1, 1024, 0, stream>>>(binh_s, NBS, boff_s, bcur_s);
    k_scan<<<1, 1024, 0, stream>>>(binh_m, NBM, boff_m, bcur_m);
    k_partition<400><<<512, 256, 0, stream>>>(sim_src, sim_dst, Es, bcur_s, binned_s);
    k_partition<32><<<256, 256, 0, stream>>>(men_src, men_dst, Em, bcur_m, binned_m);

    // layer-1 aggregations
    k_binagg<2><<<NBS * 4 * 2, 256, 0, stream>>>(binned_s, boff_s, xn0, sum_sim, Nn);
    k_binagg<8><<<NBM * 4 * 8, 256, 0, stream>>>(binned_m, boff_m, xn0, sum_men1, Nc);
    k_agg<<<256, 256, 0, stream>>>(rel_src, rel_dst, xc0, sum_rel1, Er);

    // layer-1 node updates (news in-place: must follow all xn0 readers above)
    k_news_l1<<<(Nn + 63) / 64, 256, 0, stream>>>(
        sum_sim, inv_sim, xn0, c1_Wl, c1_bl, c1_Wr, n1n_g, n1n_b, xn0, Nn);
    k_comp_l1<<<(Nc * HF + 255) / 256, 256, 0, stream>>>(
        sum_men1, inv_men, sum_rel1, inv_rel, xc0,
        c1_Wl + 4096, c1_bl + 64, c1_Wr + 4096,
        c1_Wl + 8192, c1_bl + 128, c1_Wr + 8192,
        n1c_g, n1c_b, xc, Nc);

    // layer-2 aggregations (reuse binned lists)
    k_binagg<8><<<NBM * 4 * 8, 256, 0, stream>>>(binned_m, boff_m, xn0, sum_men2, Nc);
    k_agg<<<256, 256, 0, stream>>>(rel_src, rel_dst, xc, sum_rel2, Er);

    k_final<<<(Nc * HF + 255) / 256, 256, 0, stream>>>(
        sum_men2, inv_men, sum_rel2, inv_rel, xc,
        c2_Wl + 4096, c2_bl + 64, c2_Wr + 4096,
        c2_Wl + 8192, c2_bl + 128, c2_Wr + 8192,
        cls_W1, cls_b1, cls_W2, cls_b2, (float*)d_out, Nc);
}

// Round 7
// 2030.181 us; speedup vs baseline: 1.4982x; 1.4982x over previous
//
#include <hip/hip_runtime.h>
#include <hip/hip_bf16.h>

#define HF 64

// f32 -> bf16 bits (RTNE)
__device__ __forceinline__ unsigned short f2b(float f) {
    unsigned u = __float_as_uint(f);
    u += 0x7FFFu + ((u >> 16) & 1u);
    return (unsigned short)(u >> 16);
}
// bf16 bits -> f32 (exact)
__device__ __forceinline__ float b2f(unsigned short b) {
    return __uint_as_float((unsigned)b << 16);
}

// ---------------- proj news: relu([M,385] @ [385,64] + b), writes f32 + bf16 ----------------
__global__ __launch_bounds__(256) void k_proj_news(
    const float* __restrict__ A, const float* __restrict__ W,
    const float* __restrict__ b, float* __restrict__ out,
    unsigned short* __restrict__ outb, int M)
{
    __shared__ float As[16][68];
    __shared__ float Ws[16][64];
    const int t = threadIdx.x;
    const int r0 = blockIdx.x * 64;
    const int rt = t >> 4, ct = t & 15;
    float acc[4][4] = {};

    for (int c0 = 0; c0 < 385; c0 += 16) {
        int lr = t >> 2, lk0 = (t & 3) * 4;
        #pragma unroll
        for (int j = 0; j < 4; ++j) {
            int k = c0 + lk0 + j;
            float v = 0.f;
            if ((r0 + lr) < M && k < 385) v = A[(size_t)(r0 + lr) * 385 + k];
            As[lk0 + j][lr] = v;
        }
        #pragma unroll
        for (int j = 0; j < 4; ++j) {
            int idx = j * 256 + t;
            int k = idx >> 6, col = idx & 63;
            float v = 0.f;
            if (c0 + k < 385) v = W[(size_t)(c0 + k) * 64 + col];
            Ws[k][col] = v;
        }
        __syncthreads();
        #pragma unroll
        for (int kk = 0; kk < 16; ++kk) {
            float4 a = *(const float4*)&As[kk][rt * 4];
            float4 w = *(const float4*)&Ws[kk][ct * 4];
            float av[4] = {a.x, a.y, a.z, a.w};
            float wv[4] = {w.x, w.y, w.z, w.w};
            #pragma unroll
            for (int i = 0; i < 4; ++i)
                #pragma unroll
                for (int j = 0; j < 4; ++j)
                    acc[i][j] += av[i] * wv[j];
        }
        __syncthreads();
    }
    float4 bv = *(const float4*)&b[ct * 4];
    float bb[4] = {bv.x, bv.y, bv.z, bv.w};
    #pragma unroll
    for (int i = 0; i < 4; ++i) {
        int row = r0 + rt * 4 + i;
        if (row < M) {
            float4 o;
            o.x = fmaxf(acc[i][0] + bb[0], 0.f);
            o.y = fmaxf(acc[i][1] + bb[1], 0.f);
            o.z = fmaxf(acc[i][2] + bb[2], 0.f);
            o.w = fmaxf(acc[i][3] + bb[3], 0.f);
            *(float4*)&out[(size_t)row * HF + ct * 4] = o;
            ushort4 ob;
            ob.x = f2b(o.x); ob.y = f2b(o.y); ob.z = f2b(o.z); ob.w = f2b(o.w);
            *(ushort4*)&outb[(size_t)row * HF + ct * 4] = ob;
        }
    }
}

// ---------------- proj company: writes f32 + bf16 ----------------
__global__ __launch_bounds__(256) void k_proj_comp(
    const float* __restrict__ A, const float* __restrict__ W,
    const float* __restrict__ b, float* __restrict__ out,
    unsigned short* __restrict__ outb, int M)
{
    int idx = blockIdx.x * blockDim.x + threadIdx.x;
    if (idx >= M * HF) return;
    int row = idx >> 6, col = idx & 63;
    float acc = b[col];
    #pragma unroll
    for (int k = 0; k < 24; ++k)
        acc += A[(size_t)row * 24 + k] * W[k * HF + col];
    float o = fmaxf(acc, 0.f);
    out[idx] = o;
    outb[idx] = f2b(o);
}

// ---------------- per-dst edge count ----------------
__global__ void k_count(const int* __restrict__ dst, int n, int base,
                        unsigned* __restrict__ cnt)
{
    for (int i = blockIdx.x * blockDim.x + threadIdx.x; i < n;
         i += gridDim.x * blockDim.x)
        atomicAdd(&cnt[base + dst[i]], 1u);
}

// ---------------- inv = 1/max(cnt,1) ----------------
__global__ void k_inv(const unsigned* __restrict__ cnt, float* __restrict__ inv, int n)
{
    int i = blockIdx.x * blockDim.x + threadIdx.x;
    if (i < n) inv[i] = 1.0f / fmaxf((float)cnt[i], 1.0f);
}

// ---------------- atomic scatter aggregation, bf16 source rows, 2-wide ----------------
__global__ __launch_bounds__(256) void k_aggb(
    const int* __restrict__ src, const int* __restrict__ dst,
    const unsigned short* __restrict__ x, float* __restrict__ sum, int n)
{
    const int lane = threadIdx.x & 63;
    int w = (blockIdx.x * blockDim.x + threadIdx.x) >> 6;
    const int nw = (gridDim.x * blockDim.x) >> 6;
    for (int e = w * 2; e < n; e += nw * 2) {
        int s0 = src[e], d0 = dst[e];
        bool h1 = (e + 1) < n;
        int s1 = h1 ? src[e + 1] : 0;
        int d1 = h1 ? dst[e + 1] : 0;
        float v0 = b2f(x[(size_t)s0 * HF + lane]);
        float v1 = h1 ? b2f(x[(size_t)s1 * HF + lane]) : 0.f;
        atomicAdd(&sum[(size_t)d0 * HF + lane], v0);
        if (h1) atomicAdd(&sum[(size_t)d1 * HF + lane], v1);
    }
}

// ---------------- news layer-1: LN(relu(sum*inv @ Wl + bl + xn0 @ Wr)) -> bf16 only ----------------
__global__ __launch_bounds__(256) void k_news_l1(
    const float* __restrict__ sum_sim, const float* __restrict__ invc,
    const float* __restrict__ xn0,
    const float* __restrict__ Wl, const float* __restrict__ bl,
    const float* __restrict__ Wr,
    const float* __restrict__ g, const float* __restrict__ be,
    unsigned short* __restrict__ xnb, int M)
{
    __shared__ float A1[64][68];
    __shared__ float A2[64][68];
    const int t = threadIdx.x;
    const int r0 = blockIdx.x * 64;
    const int lrow = t & 63;
    const int wq = t >> 6;

    bool rok = (r0 + lrow) < M;
    float invr = rok ? invc[r0 + lrow] : 0.f;
    #pragma unroll
    for (int j4 = 0; j4 < 4; ++j4) {
        int k0 = wq * 16 + j4 * 4;
        float4 v1 = make_float4(0.f, 0.f, 0.f, 0.f), v2 = v1;
        if (rok) {
            v1 = *(const float4*)&sum_sim[(size_t)(r0 + lrow) * HF + k0];
            v2 = *(const float4*)&xn0[(size_t)(r0 + lrow) * HF + k0];
        }
        A1[k0 + 0][lrow] = v1.x * invr; A1[k0 + 1][lrow] = v1.y * invr;
        A1[k0 + 2][lrow] = v1.z * invr; A1[k0 + 3][lrow] = v1.w * invr;
        A2[k0 + 0][lrow] = v2.x; A2[k0 + 1][lrow] = v2.y;
        A2[k0 + 2][lrow] = v2.z; A2[k0 + 3][lrow] = v2.w;
    }
    __syncthreads();

    const int rt = t >> 4, ct = t & 15;
    float acc[4][4] = {};
    #pragma unroll 16
    for (int kk = 0; kk < 64; ++kk) {
        float4 a1 = *(const float4*)&A1[kk][rt * 4];
        float4 a2 = *(const float4*)&A2[kk][rt * 4];
        float4 wl = *(const float4*)&Wl[(size_t)kk * HF + ct * 4];
        float4 wr = *(const float4*)&Wr[(size_t)kk * HF + ct * 4];
        float a1v[4] = {a1.x, a1.y, a1.z, a1.w};
        float a2v[4] = {a2.x, a2.y, a2.z, a2.w};
        float wlv[4] = {wl.x, wl.y, wl.z, wl.w};
        float wrv[4] = {wr.x, wr.y, wr.z, wr.w};
        #pragma unroll
        for (int i = 0; i < 4; ++i)
            #pragma unroll
            for (int j = 0; j < 4; ++j)
                acc[i][j] += a1v[i] * wlv[j] + a2v[i] * wrv[j];
    }
    __syncthreads();
    float (*C)[68] = A1;
    float4 blv = *(const float4*)&bl[ct * 4];
    float blb[4] = {blv.x, blv.y, blv.z, blv.w};
    #pragma unroll
    for (int i = 0; i < 4; ++i) {
        float4 o;
        o.x = fmaxf(acc[i][0] + blb[0], 0.f);
        o.y = fmaxf(acc[i][1] + blb[1], 0.f);
        o.z = fmaxf(acc[i][2] + blb[2], 0.f);
        o.w = fmaxf(acc[i][3] + blb[3], 0.f);
        *(float4*)&C[rt * 4 + i][ct * 4] = o;
    }
    __syncthreads();

    const int lane = t & 63, wid = t >> 6;
    float gl = g[lane], bel = be[lane];
    for (int rr = 0; rr < 16; ++rr) {
        int row = wid * 16 + rr;
        float v = C[row][lane];
        float s = v, q = v * v;
        #pragma unroll
        for (int m = 1; m < 64; m <<= 1) {
            s += __shfl_xor(s, m, 64);
            q += __shfl_xor(q, m, 64);
        }
        float mean = s * (1.f / 64.f);
        float var = q * (1.f / 64.f) - mean * mean;
        float r = rsqrtf(var + 1e-5f);
        int grow = r0 + row;
        if (grow < M)
            xnb[(size_t)grow * HF + lane] = f2b((v - mean) * r * gl + bel);
    }
}

// ---------------- company layer-1: writes f32 + bf16 ----------------
__global__ __launch_bounds__(256) void k_comp_l1(
    const float* __restrict__ sum_men, const float* __restrict__ inv_men,
    const float* __restrict__ sum_rel, const float* __restrict__ inv_rel,
    const float* __restrict__ xc0,
    const float* __restrict__ Wl1, const float* __restrict__ bl1,
    const float* __restrict__ Wr1,
    const float* __restrict__ Wl2, const float* __restrict__ bl2,
    const float* __restrict__ Wr2,
    const float* __restrict__ g, const float* __restrict__ be,
    float* __restrict__ xc, unsigned short* __restrict__ xcb, int M)
{
    const int lane = threadIdx.x & 63;
    const int node = (int)((blockIdx.x * blockDim.x + threadIdx.x) >> 6);
    if (node >= M) return;
    float mm = sum_men[(size_t)node * HF + lane] * inv_men[node];
    float mr = sum_rel[(size_t)node * HF + lane] * inv_rel[node];
    float xv = xc0[(size_t)node * HF + lane];
    float acc = bl1[lane] + bl2[lane];
    #pragma unroll 8
    for (int k = 0; k < 64; ++k) {
        float amm = __shfl(mm, k, 64);
        float amr = __shfl(mr, k, 64);
        float ax  = __shfl(xv, k, 64);
        acc += amm * Wl1[k * HF + lane] + ax * Wr1[k * HF + lane]
             + amr * Wl2[k * HF + lane] + ax * Wr2[k * HF + lane];
    }
    float pre = fmaxf(acc + xv, 0.f);
    float s = pre, q = pre * pre;
    #pragma unroll
    for (int m = 1; m < 64; m <<= 1) {
        s += __shfl_xor(s, m, 64);
        q += __shfl_xor(q, m, 64);
    }
    float mean = s * (1.f / 64.f);
    float var = q * (1.f / 64.f) - mean * mean;
    float r = rsqrtf(var + 1e-5f);
    float o = (pre - mean) * r * g[lane] + be[lane];
    xc[(size_t)node * HF + lane] = o;
    xcb[(size_t)node * HF + lane] = f2b(o);
}

// ---------------- company layer-2 + classifier ----------------
__global__ __launch_bounds__(256) void k_final(
    const float* __restrict__ sum_men, const float* __restrict__ inv_men,
    const float* __restrict__ sum_rel, const float* __restrict__ inv_rel,
    const float* __restrict__ xc,
    const float* __restrict__ Wl1, const float* __restrict__ bl1,
    const float* __restrict__ Wr1,
    const float* __restrict__ Wl2, const float* __restrict__ bl2,
    const float* __restrict__ Wr2,
    const float* __restrict__ W1, const float* __restrict__ b1,
    const float* __restrict__ W2, const float* __restrict__ b2,
    float* __restrict__ out, int M)
{
    const int lane = threadIdx.x & 63;
    const int node = (int)((blockIdx.x * blockDim.x + threadIdx.x) >> 6);
    if (node >= M) return;
    float mm = sum_men[(size_t)node * HF + lane] * inv_men[node];
    float mr = sum_rel[(size_t)node * HF + lane] * inv_rel[node];
    float xv = xc[(size_t)node * HF + lane];
    float acc = bl1[lane] + bl2[lane];
    #pragma unroll 8
    for (int k = 0; k < 64; ++k) {
        float amm = __shfl(mm, k, 64);
        float amr = __shfl(mr, k, 64);
        float ax  = __shfl(xv, k, 64);
        acc += amm * Wl1[k * HF + lane] + ax * (Wr1[k * HF + lane] + Wr2[k * HF + lane])
             + amr * Wl2[k * HF + lane];
    }
    float comp = fmaxf(acc + xv, 0.f);
    const int l31 = lane & 31;
    float hacc = b1[l31];
    #pragma unroll 8
    for (int j = 0; j < 64; ++j) {
        float cj = __shfl(comp, j, 64);
        hacc += cj * W1[j * 32 + l31];
    }
    float h = fmaxf(hacc, 0.f);
    float p = (lane < 32) ? h * W2[l31] : 0.f;
    #pragma unroll
    for (int m = 16; m >= 1; m >>= 1) p += __shfl_xor(p, m, 64);
    if (lane == 0) out[node] = p + b2[0];
}

extern "C" void kernel_launch(void* const* d_in, const int* in_sizes, int n_in,
                              void* d_out, int out_size, void* d_ws, size_t ws_size,
                              hipStream_t stream)
{
    const float* x_news  = (const float*)d_in[0];
    const float* x_comp  = (const float*)d_in[1];
    const int*   edge_sim = (const int*)d_in[2];
    const int*   men_src  = (const int*)d_in[3];
    const int*   men_dst  = (const int*)d_in[4];
    const int*   edge_rel = (const int*)d_in[5];
    const float* nw_W = (const float*)d_in[6];
    const float* nw_b = (const float*)d_in[7];
    const float* cw_W = (const float*)d_in[8];
    const float* cw_b = (const float*)d_in[9];
    const float* n1n_g = (const float*)d_in[10];
    const float* n1n_b = (const float*)d_in[11];
    const float* n1c_g = (const float*)d_in[12];
    const float* n1c_b = (const float*)d_in[13];
    const float* c1_Wl = (const float*)d_in[14];
    const float* c1_bl = (const float*)d_in[15];
    const float* c1_Wr = (const float*)d_in[16];
    const float* c2_Wl = (const float*)d_in[17];
    const float* c2_bl = (const float*)d_in[18];
    const float* c2_Wr = (const float*)d_in[19];
    const float* cls_W1 = (const float*)d_in[20];
    const float* cls_b1 = (const float*)d_in[21];
    const float* cls_W2 = (const float*)d_in[22];
    const float* cls_b2 = (const float*)d_in[23];

    const int Nn = in_sizes[0] / 385;
    const int Nc = in_sizes[1] / 24;
    const int Es = in_sizes[2] / 2;
    const int Em = in_sizes[3];
    const int Er = in_sizes[5] / 2;
    const int* sim_src = edge_sim;
    const int* sim_dst = edge_sim + Es;
    const int* rel_src = edge_rel;
    const int* rel_dst = edge_rel + Er;

    float* ws = (float*)d_ws;
    size_t o = 0;
    // ---- zeroed region: sums + counts ----
    float* sum_sim  = ws + o; o += (size_t)Nn * HF;
    float* sum_men1 = ws + o; o += (size_t)Nc * HF;
    float* sum_rel1 = ws + o; o += (size_t)Nc * HF;
    float* sum_men2 = ws + o; o += (size_t)Nc * HF;
    float* sum_rel2 = ws + o; o += (size_t)Nc * HF;
    unsigned* cnt_all = (unsigned*)(ws + o); o += (size_t)Nn + 2 * Nc;
    const size_t zero_bytes = o * sizeof(float);
    // ---- rest ----
    float* inv_all = ws + o; o += (size_t)Nn + 2 * Nc;
    float* xn0 = ws + o; o += (size_t)Nn * HF;
    float* xc0 = ws + o; o += (size_t)Nc * HF;
    float* xc  = ws + o; o += (size_t)Nc * HF;
    unsigned short* xn0b = (unsigned short*)(ws + o); o += (size_t)Nn * HF / 2;
    unsigned short* xnb  = (unsigned short*)(ws + o); o += (size_t)Nn * HF / 2;
    unsigned short* xc0b = (unsigned short*)(ws + o); o += (size_t)Nc * HF / 2;
    unsigned short* xcb  = (unsigned short*)(ws + o); o += (size_t)Nc * HF / 2;

    float* inv_sim = inv_all;
    float* inv_men = inv_all + Nn;
    float* inv_rel = inv_all + Nn + Nc;

    hipMemsetAsync(d_ws, 0, zero_bytes, stream);

    // projections (f32 + bf16 mirrors)
    k_proj_news<<<(Nn + 63) / 64, 256, 0, stream>>>(x_news, nw_W, nw_b, xn0, xn0b, Nn);
    k_proj_comp<<<(Nc * HF + 255) / 256, 256, 0, stream>>>(x_comp, cw_W, cw_b, xc0, xc0b, Nc);

    // degree counts + inverses
    k_count<<<1024, 256, 0, stream>>>(sim_dst, Es, 0, cnt_all);
    k_count<<<512, 256, 0, stream>>>(men_dst, Em, Nn, cnt_all);
    k_count<<<256, 256, 0, stream>>>(rel_dst, Er, Nn + Nc, cnt_all);
    k_inv<<<(Nn + 2 * Nc + 255) / 256, 256, 0, stream>>>(cnt_all, inv_all, Nn + 2 * Nc);

    // layer-1 aggregations (atomic scatter, bf16 reads, f32 sums)
    k_aggb<<<2048, 256, 0, stream>>>(sim_src, sim_dst, xn0b, sum_sim, Es);
    k_aggb<<<1024, 256, 0, stream>>>(men_src, men_dst, xn0b, sum_men1, Em);
    k_aggb<<<256, 256, 0, stream>>>(rel_src, rel_dst, xc0b, sum_rel1, Er);

    // layer-1 node updates
    k_news_l1<<<(Nn + 63) / 64, 256, 0, stream>>>(
        sum_sim, inv_sim, xn0, c1_Wl, c1_bl, c1_Wr, n1n_g, n1n_b, xnb, Nn);
    k_comp_l1<<<(Nc * HF + 255) / 256, 256, 0, stream>>>(
        sum_men1, inv_men, sum_rel1, inv_rel, xc0,
        c1_Wl + 4096, c1_bl + 64, c1_Wr + 4096,
        c1_Wl + 8192, c1_bl + 128, c1_Wr + 8192,
        n1c_g, n1c_b, xc, xcb, Nc);

    // layer-2 aggregations
    k_aggb<<<1024, 256, 0, stream>>>(men_src, men_dst, xnb, sum_men2, Em);
    k_aggb<<<256, 256, 0, stream>>>(rel_src, rel_dst, xcb, sum_rel2, Er);

    k_final<<<(Nc * HF + 255) / 256, 256, 0, stream>>>(
        sum_men2, inv_men, sum_rel2, inv_rel, xc,
        c2_Wl + 4096, c2_bl + 64, c2_Wr + 4096,
        c2_Wl + 8192, c2_bl + 128, c2_Wr + 8192,
        cls_W1, cls_b1, cls_W2, cls_b2, (float*)d_out, Nc);
}